// Round 14
// baseline (209.415 us; speedup 1.0000x reference)
//
#include <hip/hip_runtime.h>
#include <hip/hip_fp8.h>

#define LRELU_SLOPE 0.2f
#define BN 64             // nodes per bucket
#define BSH 6             // log2(BN)
#define NC 2048           // bucket counters (>= ceil(N/BN) = 1563)
#define CAP 3840          // LDS edge staging per agg bucket (mean 2048, +40 sigma)
#define TILE 8192         // edges per radix block

__device__ __forceinline__ float lrelu(float x) { return x > 0.f ? x : LRELU_SLOPE * x; }
__device__ __forceinline__ float eexp(float x)  { return __expf(fminf(x, 80.f)); }

__device__ __forceinline__ unsigned short f2bf(float f) {
    unsigned u = __float_as_uint(f);
    u += 0x7FFF + ((u >> 16) & 1);          // round-to-nearest-even
    return (unsigned short)(u >> 16);
}
__device__ __forceinline__ float bf2f(unsigned short h) {
    return __uint_as_float((unsigned)h << 16);
}

typedef float fx2 __attribute__((ext_vector_type(2)));

#if __has_builtin(__builtin_amdgcn_cvt_pk_f32_fp8) && __has_builtin(__builtin_amdgcn_cvt_pk_fp8_f32)
#define HW_FP8 1
#else
#define HW_FP8 0
#endif

// decode 8 OCP e4m3 bytes (two dwords) -> 8 floats
__device__ __forceinline__ void fp8x8_to_f32(unsigned rx, unsigned ry, float* o) {
#if HW_FP8
    fx2 a = __builtin_amdgcn_cvt_pk_f32_fp8((int)rx, false);
    fx2 b = __builtin_amdgcn_cvt_pk_f32_fp8((int)rx, true);
    fx2 c = __builtin_amdgcn_cvt_pk_f32_fp8((int)ry, false);
    fx2 d = __builtin_amdgcn_cvt_pk_f32_fp8((int)ry, true);
    o[0]=a.x; o[1]=a.y; o[2]=b.x; o[3]=b.y;
    o[4]=c.x; o[5]=c.y; o[6]=d.x; o[7]=d.y;
#else
#pragma unroll
    for (int i = 0; i < 8; ++i) {
        unsigned bb = (i < 4 ? rx : ry) >> ((i & 3) * 8);
        unsigned em = bb & 0x7F;
        float f = (em >= 8) ? __uint_as_float((em << 20) + 0x3C000000u)
                            : (float)em * 0.001953125f;
        o[i] = (bb & 0x80) ? -f : f;
    }
#endif
}

// encode 4 floats -> packed e4m3 dword
__device__ __forceinline__ unsigned f32x4_to_fp8(float a, float b, float c, float d) {
#if HW_FP8
    int w = __builtin_amdgcn_cvt_pk_fp8_f32(a, b, 0, false);
    w = __builtin_amdgcn_cvt_pk_fp8_f32(c, d, w, true);
    return (unsigned)w;
#else
    __hip_fp8_e4m3 qa(a), qb(b), qc(c), qd(d);
    return (unsigned)qa.__x | ((unsigned)qb.__x << 8) |
           ((unsigned)qc.__x << 16) | ((unsigned)qd.__x << 24);
#endif
}

// ---------------------------------------------------------------------------
// KA: fused. Blocks [0, nbn): per-node packed record rec[48 B/node]:
//     per head 12 B = {8 fp8 h1 ch, bf16 a_src, pad}; plus ad1 (fp32 x4).
//     Blocks [nbn, nbn+NBLK): radix pass-1 histogram (row only).
// ---------------------------------------------------------------------------
__global__ __launch_bounds__(256) void kA(
    const float* __restrict__ x, const float* __restrict__ W1,
    const float* __restrict__ att_src1, const float* __restrict__ att_dst1,
    unsigned char* __restrict__ rec, float* __restrict__ ad1,
    const int* __restrict__ dst, int* __restrict__ hist,
    int N, int E, int nbn)
{
    __shared__ float sW[512];
    __shared__ float sAs[32], sAd[32];
    __shared__ int hl[NC];
    int tid = threadIdx.x;

    if ((int)blockIdx.x >= nbn) {
        int blk = blockIdx.x - nbn;
        for (int i = tid; i < NC; i += 256) hl[i] = 0;
        __syncthreads();
        int e0 = blk * TILE, e1 = min(e0 + TILE, E);
        for (int e = e0 + tid; e < e1; e += 256)
            atomicAdd(&hl[dst[e] >> BSH], 1);
        __syncthreads();
        for (int i = tid; i < NC; i += 256)
            hist[(size_t)blk * NC + i] = hl[i];
        return;
    }

    for (int i = tid; i < 512; i += 256) sW[i] = W1[i];
    if (tid < 32) { sAs[tid] = att_src1[tid]; sAd[tid] = att_dst1[tid]; }
    __syncthreads();
    int n = blockIdx.x * 256 + tid;
    if (n >= N) return;

    float xr[16];
    const float4* xp = (const float4*)(x + (size_t)n * 16);
    float4 v0 = xp[0], v1 = xp[1], v2 = xp[2], v3 = xp[3];
    xr[0]=v0.x; xr[1]=v0.y; xr[2]=v0.z;  xr[3]=v0.w;
    xr[4]=v1.x; xr[5]=v1.y; xr[6]=v1.z;  xr[7]=v1.w;
    xr[8]=v2.x; xr[9]=v2.y; xr[10]=v2.z; xr[11]=v2.w;
    xr[12]=v3.x;xr[13]=v3.y;xr[14]=v3.z; xr[15]=v3.w;

    float h[32];
#pragma unroll
    for (int j = 0; j < 32; ++j) {
        float acc = 0.f;
#pragma unroll
        for (int i = 0; i < 16; ++i) acc = fmaf(xr[i], sW[i * 32 + j], acc);
        h[j] = acc;
    }

    float asr[4], adr[4];
#pragma unroll
    for (int hh = 0; hh < 4; ++hh) {
        float as = 0.f, ad = 0.f;
#pragma unroll
        for (int c = 0; c < 8; ++c) {
            as = fmaf(h[hh * 8 + c], sAs[hh * 8 + c], as);
            ad = fmaf(h[hh * 8 + c], sAd[hh * 8 + c], ad);
        }
        asr[hh] = as; adr[hh] = ad;
    }

    unsigned w0[4], w1[4], w2[4];
#pragma unroll
    for (int hh = 0; hh < 4; ++hh) {
        w0[hh] = f32x4_to_fp8(h[8*hh+0], h[8*hh+1], h[8*hh+2], h[8*hh+3]);
        w1[hh] = f32x4_to_fp8(h[8*hh+4], h[8*hh+5], h[8*hh+6], h[8*hh+7]);
        w2[hh] = (unsigned)f2bf(asr[hh]);
    }
    uint4* rp = (uint4*)(rec + (size_t)n * 48);
    rp[0] = make_uint4(w0[0], w1[0], w2[0], w0[1]);
    rp[1] = make_uint4(w1[1], w2[1], w0[2], w1[2]);
    rp[2] = make_uint4(w2[2], w0[3], w1[3], w2[3]);

    *(float4*)(ad1 + (size_t)n * 4) = make_float4(adr[0], adr[1], adr[2], adr[3]);
}

// ---------------------------------------------------------------------------
// KSCAN: 16 columns per block, carry loop over row tiles of 256.
// Writes histoff (exclusive per-column) and bukcnt (column totals).
// ---------------------------------------------------------------------------
__global__ __launch_bounds__(256) void kscan(
    const int* __restrict__ hist, int* __restrict__ histoff,
    int* __restrict__ bukcnt, int NBLK)
{
    __shared__ int sm[256 * 17];
    int tid = threadIdx.x;
    int c0 = blockIdx.x * 16;
    int carry[16];
#pragma unroll
    for (int i = 0; i < 16; ++i) carry[i] = 0;
    int* myrow = sm + tid * 17;

    for (int base = 0; base < NBLK; base += 256) {
        int idx = base + tid;
        int v[16], own[16];
        if (idx < NBLK) {
            const int4* rp = (const int4*)(hist + (size_t)idx * NC + c0);
            int4 a = rp[0], b = rp[1], c = rp[2], d = rp[3];
            v[0]=a.x; v[1]=a.y; v[2]=a.z;  v[3]=a.w;
            v[4]=b.x; v[5]=b.y; v[6]=b.z;  v[7]=b.w;
            v[8]=c.x; v[9]=c.y; v[10]=c.z; v[11]=c.w;
            v[12]=d.x; v[13]=d.y; v[14]=d.z; v[15]=d.w;
        } else {
#pragma unroll
            for (int i = 0; i < 16; ++i) v[i] = 0;
        }
#pragma unroll
        for (int i = 0; i < 16; ++i) { own[i] = v[i]; myrow[i] = v[i]; }
        __syncthreads();
        for (int off = 1; off < 256; off <<= 1) {
            int t[16];
            if (tid >= off) {
                const int* nb = sm + (tid - off) * 17;
#pragma unroll
                for (int i = 0; i < 16; ++i) t[i] = nb[i];
            } else {
#pragma unroll
                for (int i = 0; i < 16; ++i) t[i] = 0;
            }
            __syncthreads();
#pragma unroll
            for (int i = 0; i < 16; ++i) { v[i] += t[i]; myrow[i] = v[i]; }
            __syncthreads();
        }
        if (idx < NBLK) {
            int4* wp = (int4*)(histoff + (size_t)idx * NC + c0);
            int e[16];
#pragma unroll
            for (int i = 0; i < 16; ++i) e[i] = carry[i] + v[i] - own[i];
            wp[0] = make_int4(e[0], e[1], e[2], e[3]);
            wp[1] = make_int4(e[4], e[5], e[6], e[7]);
            wp[2] = make_int4(e[8], e[9], e[10], e[11]);
            wp[3] = make_int4(e[12], e[13], e[14], e[15]);
        }
        const int* last = sm + 255 * 17;
#pragma unroll
        for (int i = 0; i < 16; ++i) carry[i] += last[i];
        __syncthreads();
    }
    if (tid == 0) {
        int4* bp = (int4*)(bukcnt + c0);
        bp[0] = make_int4(carry[0], carry[1], carry[2], carry[3]);
        bp[1] = make_int4(carry[4], carry[5], carry[6], carry[7]);
        bp[2] = make_int4(carry[8], carry[9], carry[10], carry[11]);
        bp[3] = make_int4(carry[12], carry[13], carry[14], carry[15]);
    }
}

// ---------------------------------------------------------------------------
// KSCANB: 1 block; exclusive scan of bukcnt (2048) -> bukoff.
// ---------------------------------------------------------------------------
__global__ __launch_bounds__(256) void kscanB(
    const int* __restrict__ bukcnt, int* __restrict__ bukoff)
{
    __shared__ int sd[256];
    int tid = threadIdx.x;
    int4 a = ((const int4*)bukcnt)[2 * tid];
    int4 c = ((const int4*)bukcnt)[2 * tid + 1];
    int tsum = a.x + a.y + a.z + a.w + c.x + c.y + c.z + c.w;
    sd[tid] = tsum; __syncthreads();
    for (int off = 1; off < 256; off <<= 1) {
        int t = (tid >= off) ? sd[tid - off] : 0; __syncthreads();
        sd[tid] += t; __syncthreads();
    }
    int excl = sd[tid] - tsum;
    int4 oa, ob;
    oa.x = excl;        oa.y = oa.x + a.x; oa.z = oa.y + a.y; oa.w = oa.z + a.z;
    ob.x = oa.w + a.w;  ob.y = ob.x + c.x; ob.z = ob.y + c.y; ob.w = ob.z + c.z;
    ((int4*)bukoff)[2 * tid] = oa;
    ((int4*)bukoff)[2 * tid + 1] = ob;
}

// ---------------------------------------------------------------------------
// Radix pass 2: block-local LDS sort, bucket-by-bucket contiguous writeout.
// ---------------------------------------------------------------------------
#define KP2_BST (TILE * 4)
#define KP2_CUR (KP2_BST + ((NC + 1) * 2 + 2))
#define KP2_LDS (KP2_CUR + NC * 4)

__global__ __launch_bounds__(512) void kpass2(
    const int* __restrict__ src, const int* __restrict__ dst,
    const int* __restrict__ hist, const int* __restrict__ histoff,
    const int* __restrict__ bukoff,
    unsigned* __restrict__ ebuk, int E)
{
    __shared__ __align__(16) unsigned char smem[KP2_LDS];
    unsigned* staged = (unsigned*)smem;                       // TILE words
    unsigned short* bstart = (unsigned short*)(smem + KP2_BST); // NC+1
    int* cur = (int*)(smem + KP2_CUR);                        // NC
    int* partial = (int*)smem;                                // 512, aliases staged

    int tid = threadIdx.x, blk = blockIdx.x;
    int4 c4 = ((const int4*)(hist + (size_t)blk * NC))[tid];
    int tsum = c4.x + c4.y + c4.z + c4.w;
    partial[tid] = tsum;
    __syncthreads();
    for (int off = 1; off < 512; off <<= 1) {
        int t = (tid >= off) ? partial[tid - off] : 0; __syncthreads();
        partial[tid] += t; __syncthreads();
    }
    int excl = partial[tid] - tsum;
    int b4 = tid * 4;
    int e0v = excl, e1v = excl + c4.x, e2v = e1v + c4.y, e3v = e2v + c4.z;
    cur[b4] = e0v; cur[b4+1] = e1v; cur[b4+2] = e2v; cur[b4+3] = e3v;
    bstart[b4]   = (unsigned short)e0v;
    bstart[b4+1] = (unsigned short)e1v;
    bstart[b4+2] = (unsigned short)e2v;
    bstart[b4+3] = (unsigned short)e3v;
    if (tid == 511) bstart[NC] = (unsigned short)(e3v + c4.w);
    __syncthreads();

    int e0 = blk * TILE, e1 = min(e0 + TILE, E);
    for (int e = e0 + tid; e < e1; e += 512) {
        int s = src[e], d = dst[e];
        int b = d >> BSH;
        int pos = atomicAdd(&cur[b], 1);
        staged[pos] = ((unsigned)(d & (BN - 1)) << 17) | (unsigned)s;
    }
    __syncthreads();

    for (int b = tid; b < NC; b += 512) {
        int p0 = bstart[b], p1 = bstart[b + 1];
        int gb = bukoff[b] + histoff[(size_t)blk * NC + b];
        for (int p = p0; p < p1; ++p)
            ebuk[gb + (p - p0)] = staged[p];
    }
}

// ---------------------------------------------------------------------------
// Per-bucket: LDS sort by local dst (for segment gather), then fused layer-1
// gather: 4 lanes/node, head-per-lane, ONE 12B record load per edge.
// No global writeback of sorted edges; no rowptr.
// ---------------------------------------------------------------------------
__global__ __launch_bounds__(256, 6) void ksort_agg1(
    const unsigned* __restrict__ ebuk, const int* __restrict__ bukoff,
    const unsigned char* __restrict__ rec, const float* __restrict__ ad1,
    const float* __restrict__ b1, const float* __restrict__ W2,
    float* __restrict__ h2, int N)
{
    __shared__ int sbuf[CAP];
    __shared__ int cnt[BN], exc[BN], cur[BN];
    __shared__ float sb[32], sw[32];
    int tid = threadIdx.x;
    int b = blockIdx.x;
    int n0 = b << BSH;
    int r0 = bukoff[b], r1 = bukoff[b + 1];
    int tot = r1 - r0;

    if (tid < 32) { sb[tid] = b1[tid]; sw[tid] = W2[tid]; }
    if (tid < BN) cnt[tid] = 0;
    __syncthreads();

    // phase 1: local-dst histogram
    for (int i = tid; i < tot; i += 256)
        atomicAdd(&cnt[ebuk[r0 + i] >> 17], 1);
    __syncthreads();

    // 64-wide scan
    if (tid < BN) exc[tid] = cnt[tid];
    __syncthreads();
    for (int off = 1; off < BN; off <<= 1) {
        int t = 0;
        if (tid < BN && tid >= off) t = exc[tid - off];
        __syncthreads();
        if (tid < BN) exc[tid] += t;
        __syncthreads();
    }
    if (tid < BN) {
        int e = exc[tid] - cnt[tid];
        exc[tid] = e;
        cur[tid] = e;
    }
    __syncthreads();

    // phase 2: LDS scatter (sorted src ids per local dst)
    for (int i = tid; i < tot; i += 256) {
        unsigned pk = ebuk[r0 + i];
        int dl = pk >> 17;
        int pos = atomicAdd(&cur[dl], 1);
        if (pos < CAP) sbuf[pos] = (int)(pk & 0x1FFFF);
    }
    __syncthreads();

    // phase 3: 4 lanes per node; lane l = head l; one uint3 per edge
    int g = tid >> 2, l = tid & 3;
    {
        int dl = g;
        int n = n0 + dl;
        if (n < N) {
            float adh = ad1[(size_t)n * 4 + l];
            uint3 rs = *(const uint3*)(rec + (size_t)n * 48 + l * 12);
            float ass = bf2f((unsigned short)(rs.z & 0xFFFF));
            float wself = eexp(lrelu(ass + adh));
            float dsum = wself;
            float acc[8], hv[8];
            fp8x8_to_f32(rs.x, rs.y, hv);
#pragma unroll
            for (int ch = 0; ch < 8; ++ch) acc[ch] = wself * hv[ch];

            int p0 = exc[dl];
            int p1 = min(p0 + cnt[dl], CAP);
            int p = p0;
            for (; p + 8 <= p1; p += 8) {
                int sidx[8];
                uint3 uv[8];
#pragma unroll
                for (int q = 0; q < 8; ++q) sidx[q] = sbuf[p + q];
#pragma unroll
                for (int q = 0; q < 8; ++q)
                    uv[q] = *(const uint3*)(rec + (size_t)sidx[q] * 48 + l * 12);
#pragma unroll
                for (int q = 0; q < 8; ++q) {
                    float ash = bf2f((unsigned short)(uv[q].z & 0xFFFF));
                    float w = eexp(lrelu(ash + adh));
                    float sv[8];
                    fp8x8_to_f32(uv[q].x, uv[q].y, sv);
                    dsum += w;
#pragma unroll
                    for (int ch = 0; ch < 8; ++ch)
                        acc[ch] = fmaf(w, sv[ch], acc[ch]);
                }
            }
            for (; p < p1; ++p) {
                int s = sbuf[p];
                uint3 r = *(const uint3*)(rec + (size_t)s * 48 + l * 12);
                float ash = bf2f((unsigned short)(r.z & 0xFFFF));
                float sv[8];
                fp8x8_to_f32(r.x, r.y, sv);
                float w = eexp(lrelu(ash + adh));
                dsum += w;
#pragma unroll
                for (int ch = 0; ch < 8; ++ch)
                    acc[ch] = fmaf(w, sv[ch], acc[ch]);
            }
            float inv = 1.f / (dsum + 1e-16f);
            float partial = 0.f;
#pragma unroll
            for (int ch = 0; ch < 8; ++ch) {
                float o = fmaf(acc[ch], inv, sb[l * 8 + ch]);
                o = o > 0.f ? o : __expf(o) - 1.f;
                partial = fmaf(o, sw[l * 8 + ch], partial);
            }
            partial += __shfl_xor(partial, 1);
            partial += __shfl_xor(partial, 2);
            if (l == 0) h2[n] = partial;
        }
    }
}

// ---------------------------------------------------------------------------
// Layer-2: bucket-block, LDS den/acc atomics (2 per edge), reads bucket-sorted
// ebuk directly — no per-node sort or rowptr needed.
// ---------------------------------------------------------------------------
__global__ __launch_bounds__(256) void kagg2(
    const unsigned* __restrict__ ebuk, const int* __restrict__ bukoff,
    const float* __restrict__ h2,
    const float* __restrict__ att_src2, const float* __restrict__ att_dst2,
    const float* __restrict__ b2, float* __restrict__ out, int N)
{
    __shared__ float h2L[BN], den[BN], acc[BN];
    int tid = threadIdx.x;
    int b = blockIdx.x;
    int n0 = b << BSH;
    float s2 = att_src2[0], d2 = att_dst2[0];

    if (tid < BN) {
        int n = n0 + tid;
        if (n < N) {
            float hv = h2[n];
            h2L[tid] = hv;
            float w = eexp(lrelu(hv * s2 + hv * d2));
            den[tid] = w;
            acc[tid] = w * hv;
        } else { h2L[tid] = 0.f; den[tid] = 0.f; acc[tid] = 0.f; }
    }
    __syncthreads();

    int r0 = bukoff[b], r1 = bukoff[b + 1];
    for (int p = r0 + tid; p < r1; p += 256) {
        unsigned pk = ebuk[p];
        int s  = (int)(pk & 0x1FFFF);
        int dl = (int)(pk >> 17);
        float hs = h2[s];
        float w = eexp(lrelu(fmaf(hs, s2, h2L[dl] * d2)));
        atomicAdd(&den[dl], w);
        atomicAdd(&acc[dl], w * hs);
    }
    __syncthreads();

    if (tid < BN) {
        int n = n0 + tid;
        if (n < N) out[n] = acc[tid] / (den[tid] + 1e-16f) + b2[0];
    }
}

extern "C" void kernel_launch(void* const* d_in, const int* in_sizes, int n_in,
                              void* d_out, int out_size, void* d_ws, size_t ws_size,
                              hipStream_t stream)
{
    const float* x        = (const float*)d_in[0];
    const int*   ei       = (const int*)d_in[1];
    const float* W1       = (const float*)d_in[2];
    const float* att_src1 = (const float*)d_in[3];
    const float* att_dst1 = (const float*)d_in[4];
    const float* b1       = (const float*)d_in[5];
    const float* W2       = (const float*)d_in[6];
    const float* att_src2 = (const float*)d_in[7];
    const float* att_dst2 = (const float*)d_in[8];
    const float* b2       = (const float*)d_in[9];

    const int N = in_sizes[0] / 16;
    const int E = in_sizes[1] / 2;
    const int* src = ei;
    const int* dst = ei + E;

    const int NBUK = (N + BN - 1) >> BSH;       // 1563
    const int NBLK = (E + TILE - 1) / TILE;     // 391
    const int nb_n = (N + 255) / 256;           // 391

    // workspace layout
    unsigned char* rec = (unsigned char*)d_ws;               // N*48 packed records
    float* ad1   = (float*)(rec + (size_t)N * 48);           // N*4 f32
    float* h2    = ad1 + (size_t)N * 4;                      // N
    int* bukcnt  = (int*)(h2 + N);                           // NC
    int* bukoff  = bukcnt + NC;                              // NC
    int* hist    = bukoff + NC;                              // NBLK*NC
    int* histoff = hist + (size_t)NBLK * NC;                 // NBLK*NC
    unsigned* ebuk = (unsigned*)(histoff + (size_t)NBLK * NC); // E

    kA<<<nb_n + NBLK, 256, 0, stream>>>(x, W1, att_src1, att_dst1,
                                        rec, ad1, dst, hist,
                                        N, E, nb_n);
    kscan<<<NC / 16, 256, 0, stream>>>(hist, histoff, bukcnt, NBLK);
    kscanB<<<1, 256, 0, stream>>>(bukcnt, bukoff);
    kpass2<<<NBLK, 512, 0, stream>>>(src, dst, hist, histoff, bukoff, ebuk, E);
    ksort_agg1<<<NBUK, 256, 0, stream>>>(ebuk, bukoff, rec, ad1,
                                         b1, W2, h2, N);
    kagg2<<<NBUK, 256, 0, stream>>>(ebuk, bukoff, h2, att_src2, att_dst2,
                                    b2, (float*)d_out, N);
}

// Round 15
// 190.224 us; speedup vs baseline: 1.1009x; 1.1009x over previous
//
#include <hip/hip_runtime.h>
#include <hip/hip_fp8.h>

#define LRELU_SLOPE 0.2f
#define BN 64             // nodes per bucket
#define BSH 6             // log2(BN)
#define NC 2048           // bucket counters (>= ceil(N/BN) = 1563)
#define CAP 3840          // LDS edge staging per agg bucket (mean 2048, +40 sigma)
#define TILE 8192         // edges per radix block

__device__ __forceinline__ float lrelu(float x) { return x > 0.f ? x : LRELU_SLOPE * x; }
__device__ __forceinline__ float eexp(float x)  { return __expf(fminf(x, 80.f)); }

__device__ __forceinline__ unsigned short f2bf(float f) {
    unsigned u = __float_as_uint(f);
    u += 0x7FFF + ((u >> 16) & 1);          // round-to-nearest-even
    return (unsigned short)(u >> 16);
}
__device__ __forceinline__ float bf2f(unsigned short h) {
    return __uint_as_float((unsigned)h << 16);
}

typedef float fx2 __attribute__((ext_vector_type(2)));

#if __has_builtin(__builtin_amdgcn_cvt_pk_f32_fp8) && __has_builtin(__builtin_amdgcn_cvt_pk_fp8_f32)
#define HW_FP8 1
#else
#define HW_FP8 0
#endif

// decode 8 OCP e4m3 bytes (two dwords) -> 8 floats
__device__ __forceinline__ void fp8x8_to_f32(unsigned rx, unsigned ry, float* o) {
#if HW_FP8
    fx2 a = __builtin_amdgcn_cvt_pk_f32_fp8((int)rx, false);
    fx2 b = __builtin_amdgcn_cvt_pk_f32_fp8((int)rx, true);
    fx2 c = __builtin_amdgcn_cvt_pk_f32_fp8((int)ry, false);
    fx2 d = __builtin_amdgcn_cvt_pk_f32_fp8((int)ry, true);
    o[0]=a.x; o[1]=a.y; o[2]=b.x; o[3]=b.y;
    o[4]=c.x; o[5]=c.y; o[6]=d.x; o[7]=d.y;
#else
#pragma unroll
    for (int i = 0; i < 8; ++i) {
        unsigned bb = (i < 4 ? rx : ry) >> ((i & 3) * 8);
        unsigned em = bb & 0x7F;
        float f = (em >= 8) ? __uint_as_float((em << 20) + 0x3C000000u)
                            : (float)em * 0.001953125f;
        o[i] = (bb & 0x80) ? -f : f;
    }
#endif
}

// encode 4 floats -> packed e4m3 dword
__device__ __forceinline__ unsigned f32x4_to_fp8(float a, float b, float c, float d) {
#if HW_FP8
    int w = __builtin_amdgcn_cvt_pk_fp8_f32(a, b, 0, false);
    w = __builtin_amdgcn_cvt_pk_fp8_f32(c, d, w, true);
    return (unsigned)w;
#else
    __hip_fp8_e4m3 qa(a), qb(b), qc(c), qd(d);
    return (unsigned)qa.__x | ((unsigned)qb.__x << 8) |
           ((unsigned)qc.__x << 16) | ((unsigned)qd.__x << 24);
#endif
}

// ---------------------------------------------------------------------------
// KA: fused. Blocks [0, nbn): per-node packed record rec[48 B/node]:
//     per head 12 B = {8 fp8 h1 ch, bf16 a_src, pad}; plus ad1 (fp32 x4).
//     Blocks [nbn, nbn+NBLK): radix pass-1 histogram (row only).
// ---------------------------------------------------------------------------
__global__ __launch_bounds__(256) void kA(
    const float* __restrict__ x, const float* __restrict__ W1,
    const float* __restrict__ att_src1, const float* __restrict__ att_dst1,
    unsigned char* __restrict__ rec, float* __restrict__ ad1,
    const int* __restrict__ dst, int* __restrict__ hist,
    int N, int E, int nbn)
{
    __shared__ float sW[512];
    __shared__ float sAs[32], sAd[32];
    __shared__ int hl[NC];
    int tid = threadIdx.x;

    if ((int)blockIdx.x >= nbn) {
        int blk = blockIdx.x - nbn;
        for (int i = tid; i < NC; i += 256) hl[i] = 0;
        __syncthreads();
        int e0 = blk * TILE, e1 = min(e0 + TILE, E);
        for (int e = e0 + tid; e < e1; e += 256)
            atomicAdd(&hl[dst[e] >> BSH], 1);
        __syncthreads();
        for (int i = tid; i < NC; i += 256)
            hist[(size_t)blk * NC + i] = hl[i];
        return;
    }

    for (int i = tid; i < 512; i += 256) sW[i] = W1[i];
    if (tid < 32) { sAs[tid] = att_src1[tid]; sAd[tid] = att_dst1[tid]; }
    __syncthreads();
    int n = blockIdx.x * 256 + tid;
    if (n >= N) return;

    float xr[16];
    const float4* xp = (const float4*)(x + (size_t)n * 16);
    float4 v0 = xp[0], v1 = xp[1], v2 = xp[2], v3 = xp[3];
    xr[0]=v0.x; xr[1]=v0.y; xr[2]=v0.z;  xr[3]=v0.w;
    xr[4]=v1.x; xr[5]=v1.y; xr[6]=v1.z;  xr[7]=v1.w;
    xr[8]=v2.x; xr[9]=v2.y; xr[10]=v2.z; xr[11]=v2.w;
    xr[12]=v3.x;xr[13]=v3.y;xr[14]=v3.z; xr[15]=v3.w;

    float h[32];
#pragma unroll
    for (int j = 0; j < 32; ++j) {
        float acc = 0.f;
#pragma unroll
        for (int i = 0; i < 16; ++i) acc = fmaf(xr[i], sW[i * 32 + j], acc);
        h[j] = acc;
    }

    float asr[4], adr[4];
#pragma unroll
    for (int hh = 0; hh < 4; ++hh) {
        float as = 0.f, ad = 0.f;
#pragma unroll
        for (int c = 0; c < 8; ++c) {
            as = fmaf(h[hh * 8 + c], sAs[hh * 8 + c], as);
            ad = fmaf(h[hh * 8 + c], sAd[hh * 8 + c], ad);
        }
        asr[hh] = as; adr[hh] = ad;
    }

    unsigned w0[4], w1[4], w2[4];
#pragma unroll
    for (int hh = 0; hh < 4; ++hh) {
        w0[hh] = f32x4_to_fp8(h[8*hh+0], h[8*hh+1], h[8*hh+2], h[8*hh+3]);
        w1[hh] = f32x4_to_fp8(h[8*hh+4], h[8*hh+5], h[8*hh+6], h[8*hh+7]);
        w2[hh] = (unsigned)f2bf(asr[hh]);
    }
    uint4* rp = (uint4*)(rec + (size_t)n * 48);
    rp[0] = make_uint4(w0[0], w1[0], w2[0], w0[1]);
    rp[1] = make_uint4(w1[1], w2[1], w0[2], w1[2]);
    rp[2] = make_uint4(w2[2], w0[3], w1[3], w2[3]);

    *(float4*)(ad1 + (size_t)n * 4) = make_float4(adr[0], adr[1], adr[2], adr[3]);
}

// ---------------------------------------------------------------------------
// KSCAN: 16 columns per block, carry loop over row tiles of 256.
// Writes histoff (exclusive per-column) and bukcnt (column totals).
// ---------------------------------------------------------------------------
__global__ __launch_bounds__(256) void kscan(
    const int* __restrict__ hist, int* __restrict__ histoff,
    int* __restrict__ bukcnt, int NBLK)
{
    __shared__ int sm[256 * 17];
    int tid = threadIdx.x;
    int c0 = blockIdx.x * 16;
    int carry[16];
#pragma unroll
    for (int i = 0; i < 16; ++i) carry[i] = 0;
    int* myrow = sm + tid * 17;

    for (int base = 0; base < NBLK; base += 256) {
        int idx = base + tid;
        int v[16], own[16];
        if (idx < NBLK) {
            const int4* rp = (const int4*)(hist + (size_t)idx * NC + c0);
            int4 a = rp[0], b = rp[1], c = rp[2], d = rp[3];
            v[0]=a.x; v[1]=a.y; v[2]=a.z;  v[3]=a.w;
            v[4]=b.x; v[5]=b.y; v[6]=b.z;  v[7]=b.w;
            v[8]=c.x; v[9]=c.y; v[10]=c.z; v[11]=c.w;
            v[12]=d.x; v[13]=d.y; v[14]=d.z; v[15]=d.w;
        } else {
#pragma unroll
            for (int i = 0; i < 16; ++i) v[i] = 0;
        }
#pragma unroll
        for (int i = 0; i < 16; ++i) { own[i] = v[i]; myrow[i] = v[i]; }
        __syncthreads();
        for (int off = 1; off < 256; off <<= 1) {
            int t[16];
            if (tid >= off) {
                const int* nb = sm + (tid - off) * 17;
#pragma unroll
                for (int i = 0; i < 16; ++i) t[i] = nb[i];
            } else {
#pragma unroll
                for (int i = 0; i < 16; ++i) t[i] = 0;
            }
            __syncthreads();
#pragma unroll
            for (int i = 0; i < 16; ++i) { v[i] += t[i]; myrow[i] = v[i]; }
            __syncthreads();
        }
        if (idx < NBLK) {
            int4* wp = (int4*)(histoff + (size_t)idx * NC + c0);
            int e[16];
#pragma unroll
            for (int i = 0; i < 16; ++i) e[i] = carry[i] + v[i] - own[i];
            wp[0] = make_int4(e[0], e[1], e[2], e[3]);
            wp[1] = make_int4(e[4], e[5], e[6], e[7]);
            wp[2] = make_int4(e[8], e[9], e[10], e[11]);
            wp[3] = make_int4(e[12], e[13], e[14], e[15]);
        }
        const int* last = sm + 255 * 17;
#pragma unroll
        for (int i = 0; i < 16; ++i) carry[i] += last[i];
        __syncthreads();
    }
    if (tid == 0) {
        int4* bp = (int4*)(bukcnt + c0);
        bp[0] = make_int4(carry[0], carry[1], carry[2], carry[3]);
        bp[1] = make_int4(carry[4], carry[5], carry[6], carry[7]);
        bp[2] = make_int4(carry[8], carry[9], carry[10], carry[11]);
        bp[3] = make_int4(carry[12], carry[13], carry[14], carry[15]);
    }
}

// ---------------------------------------------------------------------------
// KSCANB: 1 block; exclusive scan of bukcnt (2048) -> bukoff.
// ---------------------------------------------------------------------------
__global__ __launch_bounds__(256) void kscanB(
    const int* __restrict__ bukcnt, int* __restrict__ bukoff)
{
    __shared__ int sd[256];
    int tid = threadIdx.x;
    int4 a = ((const int4*)bukcnt)[2 * tid];
    int4 c = ((const int4*)bukcnt)[2 * tid + 1];
    int tsum = a.x + a.y + a.z + a.w + c.x + c.y + c.z + c.w;
    sd[tid] = tsum; __syncthreads();
    for (int off = 1; off < 256; off <<= 1) {
        int t = (tid >= off) ? sd[tid - off] : 0; __syncthreads();
        sd[tid] += t; __syncthreads();
    }
    int excl = sd[tid] - tsum;
    int4 oa, ob;
    oa.x = excl;        oa.y = oa.x + a.x; oa.z = oa.y + a.y; oa.w = oa.z + a.z;
    ob.x = oa.w + a.w;  ob.y = ob.x + c.x; ob.z = ob.y + c.y; ob.w = ob.z + c.z;
    ((int4*)bukoff)[2 * tid] = oa;
    ((int4*)bukoff)[2 * tid + 1] = ob;
}

// ---------------------------------------------------------------------------
// Radix pass 2: block-local LDS sort, bucket-by-bucket contiguous writeout.
// ---------------------------------------------------------------------------
#define KP2_BST (TILE * 4)
#define KP2_CUR (KP2_BST + ((NC + 1) * 2 + 2))
#define KP2_LDS (KP2_CUR + NC * 4)

__global__ __launch_bounds__(512) void kpass2(
    const int* __restrict__ src, const int* __restrict__ dst,
    const int* __restrict__ hist, const int* __restrict__ histoff,
    const int* __restrict__ bukoff,
    unsigned* __restrict__ ebuk, int E)
{
    __shared__ __align__(16) unsigned char smem[KP2_LDS];
    unsigned* staged = (unsigned*)smem;                       // TILE words
    unsigned short* bstart = (unsigned short*)(smem + KP2_BST); // NC+1
    int* cur = (int*)(smem + KP2_CUR);                        // NC
    int* partial = (int*)smem;                                // 512, aliases staged

    int tid = threadIdx.x, blk = blockIdx.x;
    int4 c4 = ((const int4*)(hist + (size_t)blk * NC))[tid];
    int tsum = c4.x + c4.y + c4.z + c4.w;
    partial[tid] = tsum;
    __syncthreads();
    for (int off = 1; off < 512; off <<= 1) {
        int t = (tid >= off) ? partial[tid - off] : 0; __syncthreads();
        partial[tid] += t; __syncthreads();
    }
    int excl = partial[tid] - tsum;
    int b4 = tid * 4;
    int e0v = excl, e1v = excl + c4.x, e2v = e1v + c4.y, e3v = e2v + c4.z;
    cur[b4] = e0v; cur[b4+1] = e1v; cur[b4+2] = e2v; cur[b4+3] = e3v;
    bstart[b4]   = (unsigned short)e0v;
    bstart[b4+1] = (unsigned short)e1v;
    bstart[b4+2] = (unsigned short)e2v;
    bstart[b4+3] = (unsigned short)e3v;
    if (tid == 511) bstart[NC] = (unsigned short)(e3v + c4.w);
    __syncthreads();

    int e0 = blk * TILE, e1 = min(e0 + TILE, E);
    for (int e = e0 + tid; e < e1; e += 512) {
        int s = src[e], d = dst[e];
        int b = d >> BSH;
        int pos = atomicAdd(&cur[b], 1);
        staged[pos] = ((unsigned)(d & (BN - 1)) << 17) | (unsigned)s;
    }
    __syncthreads();

    for (int b = tid; b < NC; b += 512) {
        int p0 = bstart[b], p1 = bstart[b + 1];
        int gb = bukoff[b] + histoff[(size_t)blk * NC + b];
        for (int p = p0; p < p1; ++p)
            ebuk[gb + (p - p0)] = staged[p];
    }
}

// ---------------------------------------------------------------------------
// Per-bucket: LDS sort by local dst, in-place writeback, rowptr, then fused
// layer-1 gather: 4 lanes/node, head-per-lane, ONE 12B record load per edge.
// ---------------------------------------------------------------------------
__global__ __launch_bounds__(256, 6) void ksort_agg1(
    unsigned* __restrict__ ebuk, const int* __restrict__ bukoff,
    const unsigned char* __restrict__ rec, const float* __restrict__ ad1,
    const float* __restrict__ b1, const float* __restrict__ W2,
    float* __restrict__ h2, int* __restrict__ rowptr, int N)
{
    __shared__ int sbuf[CAP];
    __shared__ int cnt[BN], exc[BN], cur[BN];
    __shared__ float sb[32], sw[32];
    int tid = threadIdx.x;
    int b = blockIdx.x;
    int n0 = b << BSH;
    int r0 = bukoff[b], r1 = bukoff[b + 1];
    int tot = r1 - r0;

    if (tid < 32) { sb[tid] = b1[tid]; sw[tid] = W2[tid]; }
    if (tid < BN) cnt[tid] = 0;
    __syncthreads();

    // phase 1: local-dst histogram
    for (int i = tid; i < tot; i += 256)
        atomicAdd(&cnt[ebuk[r0 + i] >> 17], 1);
    __syncthreads();

    // 64-wide scan
    if (tid < BN) exc[tid] = cnt[tid];
    __syncthreads();
    for (int off = 1; off < BN; off <<= 1) {
        int t = 0;
        if (tid < BN && tid >= off) t = exc[tid - off];
        __syncthreads();
        if (tid < BN) exc[tid] += t;
        __syncthreads();
    }
    if (tid < BN) {
        int e = exc[tid] - cnt[tid];
        exc[tid] = e;
        cur[tid] = e;
        int n = n0 + tid;
        if (n <= N) rowptr[n] = r0 + e;
    }
    __syncthreads();

    // phase 2: LDS scatter + coalesced writeback (sorted src ids)
    for (int i = tid; i < tot; i += 256) {
        unsigned pk = ebuk[r0 + i];
        int dl = pk >> 17;
        int pos = atomicAdd(&cur[dl], 1);
        if (pos < CAP) sbuf[pos] = (int)(pk & 0x1FFFF);
    }
    __syncthreads();
    for (int i = tid; i < tot; i += 256)
        ebuk[r0 + i] = (unsigned)sbuf[min(i, CAP - 1)];

    // phase 3: 4 lanes per node; lane l = head l; one uint3 per edge
    int g = tid >> 2, l = tid & 3;
    {
        int dl = g;
        int n = n0 + dl;
        if (n < N) {
            float adh = ad1[(size_t)n * 4 + l];
            uint3 rs = *(const uint3*)(rec + (size_t)n * 48 + l * 12);
            float ass = bf2f((unsigned short)(rs.z & 0xFFFF));
            float wself = eexp(lrelu(ass + adh));
            float dsum = wself;
            float acc[8], hv[8];
            fp8x8_to_f32(rs.x, rs.y, hv);
#pragma unroll
            for (int ch = 0; ch < 8; ++ch) acc[ch] = wself * hv[ch];

            int p0 = exc[dl];
            int p1 = min(p0 + cnt[dl], CAP);
            int p = p0;
            for (; p + 8 <= p1; p += 8) {
                int sidx[8];
                uint3 uv[8];
#pragma unroll
                for (int q = 0; q < 8; ++q) sidx[q] = sbuf[p + q];
#pragma unroll
                for (int q = 0; q < 8; ++q)
                    uv[q] = *(const uint3*)(rec + (size_t)sidx[q] * 48 + l * 12);
#pragma unroll
                for (int q = 0; q < 8; ++q) {
                    float ash = bf2f((unsigned short)(uv[q].z & 0xFFFF));
                    float w = eexp(lrelu(ash + adh));
                    float sv[8];
                    fp8x8_to_f32(uv[q].x, uv[q].y, sv);
                    dsum += w;
#pragma unroll
                    for (int ch = 0; ch < 8; ++ch)
                        acc[ch] = fmaf(w, sv[ch], acc[ch]);
                }
            }
            for (; p < p1; ++p) {
                int s = sbuf[p];
                uint3 r = *(const uint3*)(rec + (size_t)s * 48 + l * 12);
                float ash = bf2f((unsigned short)(r.z & 0xFFFF));
                float sv[8];
                fp8x8_to_f32(r.x, r.y, sv);
                float w = eexp(lrelu(ash + adh));
                dsum += w;
#pragma unroll
                for (int ch = 0; ch < 8; ++ch)
                    acc[ch] = fmaf(w, sv[ch], acc[ch]);
            }
            float inv = 1.f / (dsum + 1e-16f);
            float partial = 0.f;
#pragma unroll
            for (int ch = 0; ch < 8; ++ch) {
                float o = fmaf(acc[ch], inv, sb[l * 8 + ch]);
                o = o > 0.f ? o : __expf(o) - 1.f;
                partial = fmaf(o, sw[l * 8 + ch], partial);
            }
            partial += __shfl_xor(partial, 1);
            partial += __shfl_xor(partial, 2);
            if (l == 0) h2[n] = partial;
        }
    }
}

// ---------------------------------------------------------------------------
// Layer-2 gather: 8 lanes per node, 2-edge unroll, shuffle reduction
// ---------------------------------------------------------------------------
__global__ __launch_bounds__(256) void kagg2(
    const unsigned* __restrict__ esrc, const int* __restrict__ rowptr,
    const float* __restrict__ h2,
    const float* __restrict__ att_src2, const float* __restrict__ att_dst2,
    const float* __restrict__ b2, float* __restrict__ out, int N)
{
    int tid = threadIdx.x;
    int g = tid >> 3, l = tid & 7;
    int n = blockIdx.x * 32 + g;
    if (n >= N) return;
    float s2 = att_src2[0], d2 = att_dst2[0];
    int r0 = rowptr[n], r1 = rowptr[n + 1];
    float h2d = h2[n];
    float add = h2d * d2;
    float den = 0.f, acc = 0.f;
    if (l == 0) {
        float ws = eexp(lrelu(fmaf(h2d, s2, add)));
        den = ws; acc = ws * h2d;
    }
    int p = r0 + l;
    for (; p + 8 < r1; p += 16) {
        int s0 = (int)esrc[p], s1 = (int)esrc[p + 8];
        float ha = h2[s0], hb = h2[s1];
        float wa = eexp(lrelu(fmaf(ha, s2, add)));
        float wb = eexp(lrelu(fmaf(hb, s2, add)));
        den += wa + wb;
        acc = fmaf(wa, ha, acc);
        acc = fmaf(wb, hb, acc);
    }
    if (p < r1) {
        int s = (int)esrc[p];
        float hs = h2[s];
        float w = eexp(lrelu(fmaf(hs, s2, add)));
        den += w;
        acc = fmaf(w, hs, acc);
    }
    den += __shfl_xor(den, 1); acc += __shfl_xor(acc, 1);
    den += __shfl_xor(den, 2); acc += __shfl_xor(acc, 2);
    den += __shfl_xor(den, 4); acc += __shfl_xor(acc, 4);
    if (l == 0) out[n] = acc / (den + 1e-16f) + b2[0];
}

extern "C" void kernel_launch(void* const* d_in, const int* in_sizes, int n_in,
                              void* d_out, int out_size, void* d_ws, size_t ws_size,
                              hipStream_t stream)
{
    const float* x        = (const float*)d_in[0];
    const int*   ei       = (const int*)d_in[1];
    const float* W1       = (const float*)d_in[2];
    const float* att_src1 = (const float*)d_in[3];
    const float* att_dst1 = (const float*)d_in[4];
    const float* b1       = (const float*)d_in[5];
    const float* W2       = (const float*)d_in[6];
    const float* att_src2 = (const float*)d_in[7];
    const float* att_dst2 = (const float*)d_in[8];
    const float* b2       = (const float*)d_in[9];

    const int N = in_sizes[0] / 16;
    const int E = in_sizes[1] / 2;
    const int* src = ei;
    const int* dst = ei + E;

    const int NBUK = (N + BN - 1) >> BSH;       // 1563
    const int NBLK = (E + TILE - 1) / TILE;     // 391
    const int nb_n = (N + 255) / 256;           // 391

    // workspace layout
    unsigned char* rec = (unsigned char*)d_ws;               // N*48 packed records
    float* ad1   = (float*)(rec + (size_t)N * 48);           // N*4 f32
    float* h2    = ad1 + (size_t)N * 4;                      // N
    int* rowptr  = (int*)(h2 + N);                           // N+64
    int* bukcnt  = rowptr + N + 64;                          // NC
    int* bukoff  = bukcnt + NC;                              // NC
    int* hist    = bukoff + NC;                              // NBLK*NC
    int* histoff = hist + (size_t)NBLK * NC;                 // NBLK*NC
    unsigned* ebuk = (unsigned*)(histoff + (size_t)NBLK * NC); // E

    kA<<<nb_n + NBLK, 256, 0, stream>>>(x, W1, att_src1, att_dst1,
                                        rec, ad1, dst, hist,
                                        N, E, nb_n);
    kscan<<<NC / 16, 256, 0, stream>>>(hist, histoff, bukcnt, NBLK);
    kscanB<<<1, 256, 0, stream>>>(bukcnt, bukoff);
    kpass2<<<NBLK, 512, 0, stream>>>(src, dst, hist, histoff, bukoff, ebuk, E);
    ksort_agg1<<<NBUK, 256, 0, stream>>>(ebuk, bukoff, rec, ad1,
                                         b1, W2, h2, rowptr, N);
    kagg2<<<(N + 31) / 32, 256, 0, stream>>>(ebuk, rowptr, h2,
                                             att_src2, att_dst2,
                                             b2, (float*)d_out, N);
}